// Round 1
// baseline (101.513 us; speedup 1.0000x reference)
//
#include <hip/hip_runtime.h>

#define GRAV_EPS 0.01f

__global__ __launch_bounds__(256) void DecoderGravity_33268816675213_kernel(
    const float* __restrict__ x,
    const int*   __restrict__ eli,
    const float* __restrict__ lp,
    float*       __restrict__ out,
    int E)
{
    const int STRIDE = 129;   // D1
    const int D = 128;        // position dims

    int tid  = blockIdx.x * blockDim.x + threadIdx.x;
    int edge = tid >> 5;      // 32 lanes per edge
    int lane = tid & 31;
    if (edge >= E) return;

    int s = eli[edge];        // src node
    int d = eli[E + edge];    // dst node

    const float* __restrict__ xs = x + (long)s * STRIDE;
    const float* __restrict__ xd = x + (long)d * STRIDE;

    float sum = 0.0f;
    #pragma unroll
    for (int k = 0; k < 4; ++k) {
        int idx = lane + 32 * k;          // 0..127, coalesced per 32-lane group
        float a = xs[idx];
        float b = xd[idx];
        float df = a - b;
        sum = fmaf(df, df, sum);
    }

    // Butterfly reduce across the 32-lane group (xor masks stay within half-wave)
    sum += __shfl_xor(sum, 1);
    sum += __shfl_xor(sum, 2);
    sum += __shfl_xor(sum, 4);
    sum += __shfl_xor(sum, 8);
    sum += __shfl_xor(sum, 16);

    if (lane == 0) {
        float m = xd[D];                          // mass of target node
        out[edge] = m - lp[0] * logf(sum + GRAV_EPS);
    }
}

extern "C" void kernel_launch(void* const* d_in, const int* in_sizes, int n_in,
                              void* d_out, int out_size, void* d_ws, size_t ws_size,
                              hipStream_t stream) {
    const float* x   = (const float*)d_in[0];
    const int*   eli = (const int*)d_in[1];
    const float* lp  = (const float*)d_in[2];
    float*       out = (float*)d_out;

    int E = in_sizes[1] / 2;   // edge_label_index is [2, E]

    int threads = 256;                       // 8 edges per block
    long total  = (long)E * 32;
    int blocks  = (int)((total + threads - 1) / threads);

    DecoderGravity_33268816675213_kernel<<<blocks, threads, 0, stream>>>(
        x, eli, lp, out, E);
}